// Round 1
// baseline (175.545 us; speedup 1.0000x reference)
//
#include <hip/hip_runtime.h>
#include <hip/hip_bf16.h>
#include <stdint.h>

#define EDIM 1024
#define NH 16
#define HD 64
#define WIN 256
#define BB 2
#define SS 2048
#define MR (BB*SS)      // 4096 rows
#define NQKV 3072

typedef __attribute__((ext_vector_type(8))) short short8;
typedef __attribute__((ext_vector_type(4))) float f32x4;

__device__ __forceinline__ unsigned short f2bf(float f) {
  union { float f; uint32_t u; } c; c.f = f;
  uint32_t r = (c.u + 0x7FFFu + ((c.u >> 16) & 1u)) >> 16;
  return (unsigned short)r;
}

// ---------------- fp32 -> bf16 conversion ----------------
__global__ __launch_bounds__(256) void cvt_kernel(const float* __restrict__ s,
                                                  unsigned short* __restrict__ d, int n8) {
  int i = blockIdx.x * 256 + threadIdx.x;
  if (i >= n8) return;
  const float4* s4 = (const float4*)s;
  float4 a = s4[2*i], b = s4[2*i+1];
  short8 o;
  o[0]=(short)f2bf(a.x); o[1]=(short)f2bf(a.y); o[2]=(short)f2bf(a.z); o[3]=(short)f2bf(a.w);
  o[4]=(short)f2bf(b.x); o[5]=(short)f2bf(b.y); o[6]=(short)f2bf(b.z); o[7]=(short)f2bf(b.w);
  ((short8*)d)[i] = o;
}

// ---------------- GEMM: C[M,N] = A[M,K] * Bw[N,K]^T (both row-major, K contiguous) ----
// 128x128 tile, BK=64, 4 waves (2x2), each wave 64x64 via 4x4 16x16x32 MFMA frags.
// LDS tiles [row][k] with XOR swizzle (byte ^= (row&7)<<4) applied via pre-swizzled
// global source (global_load_lds writes linearly).
template<typename OutT>
__global__ __launch_bounds__(256) void gemm_bt(const unsigned short* __restrict__ A,
                                               const unsigned short* __restrict__ Bw,
                                               OutT* __restrict__ C, int M, int N, int K) {
  __shared__ unsigned short As[128*64];
  __shared__ unsigned short Bs[128*64];
  const int t = threadIdx.x, lane = t & 63;
  const int w = t >> 6, wr = w >> 1, wc = w & 1;
  const int m0 = blockIdx.y * 128, n0 = blockIdx.x * 128;
  f32x4 acc[4][4] = {};
  for (int kt = 0; kt < K; kt += 64) {
    __syncthreads();
#pragma unroll
    for (int r = 0; r < 4; ++r) {
      const int row = r*32 + (t >> 3);
      const int colb = (((t & 7) ^ (row & 7)) << 4);   // pre-swizzled source chunk
      const int o = r*4096 + t*16;                      // linear LDS byte offset
      __builtin_amdgcn_global_load_lds(
        (const __attribute__((address_space(1))) char*)(A + (size_t)(m0 + row) * K + kt + (colb >> 1)),
        (__attribute__((address_space(3))) char*)((char*)As + o), 16, 0, 0);
      __builtin_amdgcn_global_load_lds(
        (const __attribute__((address_space(1))) char*)(Bw + (size_t)(n0 + row) * K + kt + (colb >> 1)),
        (__attribute__((address_space(3))) char*)((char*)Bs + o), 16, 0, 0);
    }
    __syncthreads();
#pragma unroll
    for (int c = 0; c < 2; ++c) {
      const int k0 = c*32 + ((lane >> 4) << 3);
      short8 af[4], bfr[4];
#pragma unroll
      for (int mi = 0; mi < 4; ++mi) {
        const int row = wr*64 + mi*16 + (lane & 15);
        const int off = ((row << 7) + (k0 << 1)) ^ ((row & 7) << 4);
        af[mi] = *(const short8*)((const char*)As + off);
      }
#pragma unroll
      for (int ni = 0; ni < 4; ++ni) {
        const int row = wc*64 + ni*16 + (lane & 15);
        const int off = ((row << 7) + (k0 << 1)) ^ ((row & 7) << 4);
        bfr[ni] = *(const short8*)((const char*)Bs + off);
      }
#pragma unroll
      for (int mi = 0; mi < 4; ++mi)
#pragma unroll
        for (int ni = 0; ni < 4; ++ni)
          acc[mi][ni] = __builtin_amdgcn_mfma_f32_16x16x32_bf16(af[mi], bfr[ni], acc[mi][ni], 0, 0, 0);
    }
  }
  // epilogue: C/D layout col=lane&15, row=(lane>>4)*4+reg
#pragma unroll
  for (int mi = 0; mi < 4; ++mi) {
    const int rb = m0 + wr*64 + mi*16 + ((lane >> 4) << 2);
#pragma unroll
    for (int ni = 0; ni < 4; ++ni) {
      const int col = n0 + wc*64 + ni*16 + (lane & 15);
#pragma unroll
      for (int reg = 0; reg < 4; ++reg) {
        const float v = acc[mi][ni][reg];
        const size_t idx = (size_t)(rb + reg) * N + col;
        if constexpr (sizeof(OutT) == 2) ((unsigned short*)C)[idx] = f2bf(v);
        else ((float*)C)[idx] = v;
      }
    }
  }
}

// ---------------- sliding-window flash attention ----------------
// grid (qt=32, bh=32), 256 threads = 4 waves, each wave owns 16 q-rows.
// qkv layout: [B*S, 3072], q cols 0..1023, k cols 1024..2047, v cols 2048..3071.
__global__ __launch_bounds__(256) void attn_kernel(const unsigned short* __restrict__ qkv,
                                                   unsigned short* __restrict__ ctx) {
  __shared__ unsigned short Ks[64*64];      // [key][d] swizzled
  __shared__ unsigned short VTs[64*64];     // [d][key] swizzled
  __shared__ unsigned short Ps[4][16*64];   // per-wave P [q][key] swizzled
  const int t = threadIdx.x, lane = t & 63, w = t >> 6;
  const int qt = blockIdx.x, bh = blockIdx.y;
  const int b = bh >> 4, h = bh & 15;
  const int q0 = qt << 6;
  const int qw0 = q0 + (w << 4);
  const unsigned short* qb = qkv + (size_t)b * SS * NQKV + h * HD;
  const unsigned short* kb = qb + EDIM;
  const unsigned short* vb = qb + 2*EDIM;
  // Q fragments (A-frag: row=lane%16, k=(lane>>4)*8+j), two 32-d chunks
  short8 aq[2];
  {
    const size_t roff = (size_t)(qw0 + (lane & 15)) * NQKV + ((lane >> 4) << 3);
    aq[0] = *(const short8*)(qb + roff);
    aq[1] = *(const short8*)(qb + roff + 32);
  }
  f32x4 oacc[4] = {};
  float mrun[4], lrun[4];
#pragma unroll
  for (int r = 0; r < 4; ++r) { mrun[r] = -1e30f; lrun[r] = 0.f; }
  const int t_lo = qt >= 4 ? qt - 4 : 0;
  for (int kt = t_lo; kt <= qt; ++kt) {
    const int kv0 = kt << 6;
    __syncthreads();
    // stage K tile [64 keys][64 d] via global_load_lds, source pre-swizzled
#pragma unroll
    for (int r = 0; r < 2; ++r) {
      const int o = r*4096 + t*16;
      const int key = o >> 7;
      const int colb = (o & 127) ^ ((key & 7) << 4);
      __builtin_amdgcn_global_load_lds(
        (const __attribute__((address_space(1))) char*)(kb + (size_t)(kv0 + key) * NQKV + (colb >> 1)),
        (__attribute__((address_space(3))) char*)((char*)Ks + o), 16, 0, 0);
    }
    // stage V transposed: VTs[d][key], swizzled; reg-staged (coalesced 16B reads)
#pragma unroll
    for (int i = 0; i < 2; ++i) {
      const int c = t + (i << 8);
      const int key = c >> 3;
      const int d0 = (c & 7) << 3;
      short8 vv = *(const short8*)(vb + (size_t)(kv0 + key) * NQKV + d0);
#pragma unroll
      for (int j = 0; j < 8; ++j) {
        const int d = d0 + j;
        const int off = ((d << 7) + (key << 1)) ^ ((d & 7) << 4);
        *(unsigned short*)((char*)VTs + off) = (unsigned short)(short)vv[j];
      }
    }
    __syncthreads();
    // QK^T: S[16 q][64 keys] as 4 col-frags
    f32x4 sc[4] = {};
#pragma unroll
    for (int kf = 0; kf < 4; ++kf) {
#pragma unroll
      for (int c = 0; c < 2; ++c) {
        const int krow = (kf << 4) + (lane & 15);
        const int k0 = (c << 5) + ((lane >> 4) << 3);
        const int off = ((krow << 7) + (k0 << 1)) ^ ((krow & 7) << 4);
        short8 bk = *(const short8*)((const char*)Ks + off);
        sc[kf] = __builtin_amdgcn_mfma_f32_16x16x32_bf16(aq[c], bk, sc[kf], 0, 0, 0);
      }
    }
    // mask + scale + online softmax (row = (lane>>4)*4+reg, col = key = lane&15 per frag)
#pragma unroll
    for (int reg = 0; reg < 4; ++reg) {
      const int qg = qw0 + ((lane >> 4) << 2) + reg;
      float sv[4];
#pragma unroll
      for (int kf = 0; kf < 4; ++kf) {
        const int kg = kv0 + (kf << 4) + (lane & 15);
        const bool ok = (kg <= qg) && (kg + WIN > qg);
        sv[kf] = ok ? sc[kf][reg] * 0.125f : -1e30f;
      }
      float pm = fmaxf(fmaxf(sv[0], sv[1]), fmaxf(sv[2], sv[3]));
      pm = fmaxf(pm, __shfl_xor(pm, 1));
      pm = fmaxf(pm, __shfl_xor(pm, 2));
      pm = fmaxf(pm, __shfl_xor(pm, 4));
      pm = fmaxf(pm, __shfl_xor(pm, 8));
      const float mn = fmaxf(mrun[reg], pm);
      const float corr = __expf(mrun[reg] - mn);  // both -1e30 -> exp(0)=1 (acc is 0, harmless)
      mrun[reg] = mn;
      float rs = 0.f;
      const int qrow = ((lane >> 4) << 2) + reg;
#pragma unroll
      for (int kf = 0; kf < 4; ++kf) {
        const float p = __expf(sv[kf] - mn);
        rs += p;
        const int key = (kf << 4) + (lane & 15);
        const int off = ((qrow << 7) + (key << 1)) ^ ((qrow & 7) << 4);
        *(unsigned short*)((char*)&Ps[w][0] + off) = f2bf(p);
      }
      rs += __shfl_xor(rs, 1);
      rs += __shfl_xor(rs, 2);
      rs += __shfl_xor(rs, 4);
      rs += __shfl_xor(rs, 8);
      lrun[reg] = lrun[reg] * corr + rs;
#pragma unroll
      for (int nf = 0; nf < 4; ++nf) oacc[nf][reg] *= corr;
    }
    // PV: ctx[16 q][64 d] += P[16 q][64 k] * V[64 k][64 d]
#pragma unroll
    for (int c2 = 0; c2 < 2; ++c2) {
      const int prow = lane & 15;
      const int k0 = (c2 << 5) + ((lane >> 4) << 3);
      const int offp = ((prow << 7) + (k0 << 1)) ^ ((prow & 7) << 4);
      short8 pa = *(const short8*)((const char*)&Ps[w][0] + offp);
#pragma unroll
      for (int nf = 0; nf < 4; ++nf) {
        const int d = (nf << 4) + (lane & 15);
        const int offv = ((d << 7) + (k0 << 1)) ^ ((d & 7) << 4);
        short8 bv = *(const short8*)((const char*)VTs + offv);
        oacc[nf] = __builtin_amdgcn_mfma_f32_16x16x32_bf16(pa, bv, oacc[nf], 0, 0, 0);
      }
    }
  }
  // normalize + write ctx (bf16)
  unsigned short* cb = ctx + (size_t)b * SS * EDIM + h * HD;
#pragma unroll
  for (int nf = 0; nf < 4; ++nf)
#pragma unroll
    for (int reg = 0; reg < 4; ++reg) {
      const int qg = qw0 + ((lane >> 4) << 2) + reg;
      const int d = (nf << 4) + (lane & 15);
      cb[(size_t)qg * EDIM + d] = f2bf(oacc[nf][reg] / lrun[reg]);
    }
}

// ---------------- launch ----------------
extern "C" void kernel_launch(void* const* d_in, const int* in_sizes, int n_in,
                              void* d_out, int out_size, void* d_ws, size_t ws_size,
                              hipStream_t stream) {
  const float* x  = (const float*)d_in[0];
  const float* Wq = (const float*)d_in[1];
  const float* Wk = (const float*)d_in[2];
  const float* Wv = (const float*)d_in[3];
  const float* Wo = (const float*)d_in[4];
  float* out = (float*)d_out;
  char* ws = (char*)d_ws;
  // workspace layout (40 MB): [0,8MB) xb (later aliased by ctx), [8,14) wqkv,
  // [14,16) wob, [16,40) qkv
  unsigned short* xb   = (unsigned short*)(ws);
  unsigned short* ctxb = (unsigned short*)(ws);              // alias: xb dead after GEMM1
  unsigned short* wqkv = (unsigned short*)(ws + (size_t)(8u << 20));
  unsigned short* wob  = (unsigned short*)(ws + (size_t)(14u << 20));
  unsigned short* qkv  = (unsigned short*)(ws + (size_t)(16u << 20));

  const int nx8 = (MR * EDIM) / 8;          // 524288
  const int nw8 = (EDIM * EDIM) / 8;        // 131072
  cvt_kernel<<<dim3(nx8 / 256), dim3(256), 0, stream>>>(x, xb, nx8);
  cvt_kernel<<<dim3(nw8 / 256), dim3(256), 0, stream>>>(Wq, wqkv, nw8);
  cvt_kernel<<<dim3(nw8 / 256), dim3(256), 0, stream>>>(Wk, wqkv + EDIM*EDIM, nw8);
  cvt_kernel<<<dim3(nw8 / 256), dim3(256), 0, stream>>>(Wv, wqkv + 2*EDIM*EDIM, nw8);
  cvt_kernel<<<dim3(nw8 / 256), dim3(256), 0, stream>>>(Wo, wob, nw8);

  gemm_bt<unsigned short><<<dim3(NQKV/128, MR/128), dim3(256), 0, stream>>>(
      xb, wqkv, qkv, MR, NQKV, EDIM);

  attn_kernel<<<dim3(SS/64, BB*NH), dim3(256), 0, stream>>>(qkv, ctxb);

  gemm_bt<float><<<dim3(EDIM/128, MR/128), dim3(256), 0, stream>>>(
      ctxb, wob, out, MR, EDIM, EDIM);
}

// Round 2
// 161.403 us; speedup vs baseline: 1.0876x; 1.0876x over previous
//
#include <hip/hip_runtime.h>
#include <hip/hip_bf16.h>
#include <stdint.h>

#define EDIM 1024
#define NH 16
#define HD 64
#define WIN 256
#define BB 2
#define SS 2048
#define MR (BB*SS)      // 4096 rows
#define NQKV 3072

typedef __attribute__((ext_vector_type(8))) short short8;
typedef __attribute__((ext_vector_type(4))) short short4v;
typedef __attribute__((ext_vector_type(4))) float f32x4;

__device__ __forceinline__ unsigned short f2bf(float f) {
  union { float f; uint32_t u; } c; c.f = f;
  uint32_t r = (c.u + 0x7FFFu + ((c.u >> 16) & 1u)) >> 16;
  return (unsigned short)r;
}

// ---------------- fused fp32 -> bf16 conversion (x, Wq, Wk, Wv, Wo) ----------------
// dst layout: [xb 8MB][wq 2MB][wk 2MB][wv 2MB][wo 2MB] contiguous bf16 chunks.
__global__ __launch_bounds__(256) void cvt_all(const float* __restrict__ x,
                                               const float* __restrict__ Wq,
                                               const float* __restrict__ Wk,
                                               const float* __restrict__ Wv,
                                               const float* __restrict__ Wo,
                                               unsigned short* __restrict__ dst) {
  const int i = blockIdx.x * 256 + threadIdx.x;   // short8 chunk index, 1048576 total
  const float* s; int off;
  if (i < 524288) { s = x; off = i; }
  else {
    const int j = i - 524288, wsel = j >> 17;
    off = j & 131071;
    s = wsel == 0 ? Wq : wsel == 1 ? Wk : wsel == 2 ? Wv : Wo;
  }
  const float4* s4 = (const float4*)s;
  float4 a = s4[2*off], b = s4[2*off+1];
  short8 o;
  o[0]=(short)f2bf(a.x); o[1]=(short)f2bf(a.y); o[2]=(short)f2bf(a.z); o[3]=(short)f2bf(a.w);
  o[4]=(short)f2bf(b.x); o[5]=(short)f2bf(b.y); o[6]=(short)f2bf(b.z); o[7]=(short)f2bf(b.w);
  ((short8*)dst)[i] = o;
}

// ---------------- GEMM: C[M,N] = A[M,K] * Bw[N,K]^T ----------------
// Tile BM x BN, BK=64, 4 waves (2x2), XOR-swizzled LDS via pre-swizzled global src.
// 1-D grid with bijective XCD swizzle (nwg % 8 == 0 required).
template<typename OutT, int BM, int BN>
__global__ __launch_bounds__(256) void gemm_bt(const unsigned short* __restrict__ A,
                                               const unsigned short* __restrict__ Bw,
                                               OutT* __restrict__ C,
                                               int M, int N, int K, int nbx) {
  constexpr int MI = BM / 32;   // fragments per wave in M (wave tile = BM/2)
  constexpr int NI = BN / 32;
  constexpr int LA = BM / 32;   // global_load_lds per thread for A tile
  constexpr int LB = BN / 32;
  __shared__ unsigned short As[BM * 64];
  __shared__ unsigned short Bs[BN * 64];
  const int t = threadIdx.x, lane = t & 63;
  const int w = t >> 6, wr = w >> 1, wc = w & 1;
  const int nwg = gridDim.x, bid = blockIdx.x;
  const int wg = (bid & 7) * (nwg >> 3) + (bid >> 3);
  const int m0 = (wg / nbx) * BM, n0 = (wg % nbx) * BN;
  f32x4 acc[MI][NI] = {};
  for (int kt = 0; kt < K; kt += 64) {
    __syncthreads();
#pragma unroll
    for (int r = 0; r < LA; ++r) {
      const int row = r*32 + (t >> 3);
      const int colb = (((t & 7) ^ (row & 7)) << 4);
      const int o = r*4096 + t*16;
      __builtin_amdgcn_global_load_lds(
        (const __attribute__((address_space(1))) char*)(A + (size_t)(m0 + row) * K + kt + (colb >> 1)),
        (__attribute__((address_space(3))) char*)((char*)As + o), 16, 0, 0);
    }
#pragma unroll
    for (int r = 0; r < LB; ++r) {
      const int row = r*32 + (t >> 3);
      const int colb = (((t & 7) ^ (row & 7)) << 4);
      const int o = r*4096 + t*16;
      __builtin_amdgcn_global_load_lds(
        (const __attribute__((address_space(1))) char*)(Bw + (size_t)(n0 + row) * K + kt + (colb >> 1)),
        (__attribute__((address_space(3))) char*)((char*)Bs + o), 16, 0, 0);
    }
    __syncthreads();
#pragma unroll
    for (int c = 0; c < 2; ++c) {
      const int k0 = c*32 + ((lane >> 4) << 3);
      short8 af[MI], bfr[NI];
#pragma unroll
      for (int mi = 0; mi < MI; ++mi) {
        const int row = wr*(BM/2) + mi*16 + (lane & 15);
        const int off = ((row << 7) + (k0 << 1)) ^ ((row & 7) << 4);
        af[mi] = *(const short8*)((const char*)As + off);
      }
#pragma unroll
      for (int ni = 0; ni < NI; ++ni) {
        const int row = wc*(BN/2) + ni*16 + (lane & 15);
        const int off = ((row << 7) + (k0 << 1)) ^ ((row & 7) << 4);
        bfr[ni] = *(const short8*)((const char*)Bs + off);
      }
#pragma unroll
      for (int mi = 0; mi < MI; ++mi)
#pragma unroll
        for (int ni = 0; ni < NI; ++ni)
          acc[mi][ni] = __builtin_amdgcn_mfma_f32_16x16x32_bf16(af[mi], bfr[ni], acc[mi][ni], 0, 0, 0);
    }
  }
#pragma unroll
  for (int mi = 0; mi < MI; ++mi) {
    const int rb = m0 + wr*(BM/2) + mi*16 + ((lane >> 4) << 2);
#pragma unroll
    for (int ni = 0; ni < NI; ++ni) {
      const int col = n0 + wc*(BN/2) + ni*16 + (lane & 15);
#pragma unroll
      for (int reg = 0; reg < 4; ++reg) {
        const float v = acc[mi][ni][reg];
        const size_t idx = (size_t)(rb + reg) * N + col;
        if constexpr (sizeof(OutT) == 2) ((unsigned short*)C)[idx] = f2bf(v);
        else ((float*)C)[idx] = v;
      }
    }
  }
}

// ---------------- sliding-window flash attention ----------------
// 1024 blocks (XCD-swizzled), 256 threads = 4 waves, wave owns 16 q-rows.
// K: [key][d] XOR-swizzled LDS. V: tr-readable subtiled LDS
//   elem(V[k][d]) = (d>>4)*1024 + ((k>>3) + ((k>>2)&1)*8)*64 + (k&3)*16 + (d&15)
// staged via global_load_lds (linear LDS dest, permuted global src), consumed
// with ds_read_b64_tr_b16.
__global__ __launch_bounds__(256) void attn_kernel(const unsigned short* __restrict__ qkv,
                                                   unsigned short* __restrict__ ctx) {
  __shared__ __align__(16) unsigned short Ks[64*64];
  __shared__ __align__(16) unsigned short VTs[64*64];
  __shared__ __align__(16) unsigned short Ps[4][16*64];
  const int t = threadIdx.x, lane = t & 63, w = t >> 6;
  const int bid = blockIdx.x;
  const int swz = (bid & 7) * 128 + (bid >> 3);      // 1024 % 8 == 0, bijective
  const int qt = swz & 31, bh = swz >> 5;
  const int b = bh >> 4, h = bh & 15;
  const int q0 = qt << 6;
  const int qw0 = q0 + (w << 4);
  const unsigned short* qb = qkv + (size_t)b * SS * NQKV + h * HD;
  const unsigned short* kb = qb + EDIM;
  const unsigned short* vb = qb + 2*EDIM;
  short8 aq[2];
  {
    const size_t roff = (size_t)(qw0 + (lane & 15)) * NQKV + ((lane >> 4) << 3);
    aq[0] = *(const short8*)(qb + roff);
    aq[1] = *(const short8*)(qb + roff + 32);
  }
  const unsigned vt0 = (unsigned)(uintptr_t)(__attribute__((address_space(3))) char*)((char*)VTs);
  const unsigned trbase = vt0 + ((lane & 15) << 3) + ((lane >> 4) << 7);
  f32x4 oacc[4] = {};
  float mrun[4], lrun[4];
#pragma unroll
  for (int r = 0; r < 4; ++r) { mrun[r] = -1e30f; lrun[r] = 0.f; }
  const int t_lo = qt >= 4 ? qt - 4 : 0;
  for (int kt = t_lo; kt <= qt; ++kt) {
    const int kv0 = kt << 6;
    __syncthreads();
    // K tile [64 keys][64 d], XOR-swizzled via pre-swizzled source
#pragma unroll
    for (int r = 0; r < 2; ++r) {
      const int o = r*4096 + t*16;
      const int key = o >> 7;
      const int colb = (o & 127) ^ ((key & 7) << 4);
      __builtin_amdgcn_global_load_lds(
        (const __attribute__((address_space(1))) char*)(kb + (size_t)(kv0 + key) * NQKV + (colb >> 1)),
        (__attribute__((address_space(3))) char*)((char*)Ks + o), 16, 0, 0);
    }
    // V tile into subtiled layout: linear LDS dest chunk p8, decoded global src
#pragma unroll
    for (int i = 0; i < 2; ++i) {
      const int p8 = (w << 6) + lane + (i << 8);
      const int band = p8 >> 7, rr = p8 & 127, ordv = rr >> 3, q8 = rr & 7;
      const int k = ((ordv & 7) << 3) + ((ordv >> 3) << 2) + (q8 >> 1);
      const int d = (band << 4) + ((q8 & 1) << 3);
      __builtin_amdgcn_global_load_lds(
        (const __attribute__((address_space(1))) char*)(vb + (size_t)(kv0 + k) * NQKV + d),
        (__attribute__((address_space(3))) char*)((char*)VTs + p8*16), 16, 0, 0);
    }
    __syncthreads();
    // QK^T
    f32x4 sc[4] = {};
    __builtin_amdgcn_s_setprio(1);
#pragma unroll
    for (int kf = 0; kf < 4; ++kf) {
#pragma unroll
      for (int c = 0; c < 2; ++c) {
        const int krow = (kf << 4) + (lane & 15);
        const int k0 = (c << 5) + ((lane >> 4) << 3);
        const int off = ((krow << 7) + (k0 << 1)) ^ ((krow & 7) << 4);
        short8 bk = *(const short8*)((const char*)Ks + off);
        sc[kf] = __builtin_amdgcn_mfma_f32_16x16x32_bf16(aq[c], bk, sc[kf], 0, 0, 0);
      }
    }
    __builtin_amdgcn_s_setprio(0);
    // mask + online softmax; P -> LDS (bf16)
#pragma unroll
    for (int reg = 0; reg < 4; ++reg) {
      const int qg = qw0 + ((lane >> 4) << 2) + reg;
      float sv[4];
#pragma unroll
      for (int kf = 0; kf < 4; ++kf) {
        const int kg = kv0 + (kf << 4) + (lane & 15);
        const bool ok = (kg <= qg) && (kg + WIN > qg);
        sv[kf] = ok ? sc[kf][reg] * 0.125f : -1e30f;
      }
      float pm = fmaxf(fmaxf(sv[0], sv[1]), fmaxf(sv[2], sv[3]));
      pm = fmaxf(pm, __shfl_xor(pm, 1));
      pm = fmaxf(pm, __shfl_xor(pm, 2));
      pm = fmaxf(pm, __shfl_xor(pm, 4));
      pm = fmaxf(pm, __shfl_xor(pm, 8));
      const float mn = fmaxf(mrun[reg], pm);
      const float corr = __expf(mrun[reg] - mn);
      mrun[reg] = mn;
      float rs = 0.f;
      const int qrow = ((lane >> 4) << 2) + reg;
#pragma unroll
      for (int kf = 0; kf < 4; ++kf) {
        const float p = __expf(sv[kf] - mn);
        rs += p;
        const int key = (kf << 4) + (lane & 15);
        const int off = ((qrow << 7) + (key << 1)) ^ ((qrow & 7) << 4);
        *(unsigned short*)((char*)&Ps[w][0] + off) = f2bf(p);
      }
      rs += __shfl_xor(rs, 1);
      rs += __shfl_xor(rs, 2);
      rs += __shfl_xor(rs, 4);
      rs += __shfl_xor(rs, 8);
      lrun[reg] = lrun[reg] * corr + rs;
#pragma unroll
      for (int nf = 0; nf < 4; ++nf) oacc[nf][reg] *= corr;
    }
    // PV via hardware transpose reads of V
#pragma unroll
    for (int c2 = 0; c2 < 2; ++c2) {
      const int prow = lane & 15;
      const int k0 = (c2 << 5) + ((lane >> 4) << 3);
      const int offp = ((prow << 7) + (k0 << 1)) ^ ((prow & 7) << 4);
      short8 pa = *(const short8*)((const char*)&Ps[w][0] + offp);
      short4v lo[4], hi[4];
#pragma unroll
      for (int nf = 0; nf < 4; ++nf) {
        const unsigned a1 = trbase + (nf << 11) + (c2 << 9);
        asm volatile("ds_read_b64_tr_b16 %0, %1" : "=&v"(lo[nf]) : "v"(a1));
        asm volatile("ds_read_b64_tr_b16 %0, %1 offset:1024" : "=&v"(hi[nf]) : "v"(a1));
      }
      asm volatile("s_waitcnt lgkmcnt(0)" ::: "memory");
      __builtin_amdgcn_sched_barrier(0);
      __builtin_amdgcn_s_setprio(1);
#pragma unroll
      for (int nf = 0; nf < 4; ++nf) {
        short8 bv = __builtin_shufflevector(lo[nf], hi[nf], 0, 1, 2, 3, 4, 5, 6, 7);
        oacc[nf] = __builtin_amdgcn_mfma_f32_16x16x32_bf16(pa, bv, oacc[nf], 0, 0, 0);
      }
      __builtin_amdgcn_s_setprio(0);
    }
  }
  unsigned short* cb = ctx + (size_t)b * SS * EDIM + h * HD;
#pragma unroll
  for (int nf = 0; nf < 4; ++nf)
#pragma unroll
    for (int reg = 0; reg < 4; ++reg) {
      const int qg = qw0 + ((lane >> 4) << 2) + reg;
      const int d = (nf << 4) + (lane & 15);
      cb[(size_t)qg * EDIM + d] = f2bf(oacc[nf][reg] / lrun[reg]);
    }
}

// ---------------- launch ----------------
extern "C" void kernel_launch(void* const* d_in, const int* in_sizes, int n_in,
                              void* d_out, int out_size, void* d_ws, size_t ws_size,
                              hipStream_t stream) {
  const float* x  = (const float*)d_in[0];
  const float* Wq = (const float*)d_in[1];
  const float* Wk = (const float*)d_in[2];
  const float* Wv = (const float*)d_in[3];
  const float* Wo = (const float*)d_in[4];
  float* out = (float*)d_out;
  char* ws = (char*)d_ws;
  // ws layout: [0,8MB) xb (aliased by ctx later), [8,14) wqkv, [14,16) wob, [16,40) qkv
  unsigned short* xb   = (unsigned short*)(ws);
  unsigned short* ctxb = (unsigned short*)(ws);
  unsigned short* wqkv = (unsigned short*)(ws + (size_t)(8u << 20));
  unsigned short* wob  = (unsigned short*)(ws + (size_t)(14u << 20));
  unsigned short* qkv  = (unsigned short*)(ws + (size_t)(16u << 20));

  cvt_all<<<dim3(4096), dim3(256), 0, stream>>>(x, Wq, Wk, Wv, Wo, xb);

  gemm_bt<unsigned short, 128, 128><<<dim3(768), dim3(256), 0, stream>>>(
      xb, wqkv, qkv, MR, NQKV, EDIM, NQKV/128);

  attn_kernel<<<dim3(1024), dim3(256), 0, stream>>>(qkv, ctxb);

  gemm_bt<float, 128, 64><<<dim3(512), dim3(256), 0, stream>>>(
      ctxb, wob, out, MR, EDIM, EDIM, EDIM/64);
}